// Round 4
// baseline (128.217 us; speedup 1.0000x reference)
//
#include <hip/hip_runtime.h>
#include <hip/hip_bf16.h>
#include <math.h>

#define N 256
#define D 512
#define C 16
#define NBINS 1000
#define MCELL 1000
#define EPSF 1e-9f
// -50/ln(2): exp(-50*q^2) = exp2(KEXP2*q^2)
#define KEXP2 -72.134752f
#define NPART 16          // moment partial blocks per matrix
#define PSTRIDE 6144      // 6 * 1024 floats per partial

__device__ inline float waveReduceSum(float v) {
#pragma unroll
    for (int off = 32; off > 0; off >>= 1) v += __shfl_down(v, off, 64);
    return v;
}
__device__ inline double waveReduceSumD(double v) {
#pragma unroll
    for (int off = 32; off > 0; off >>= 1) v += __shfl_down(v, off, 64);
    return v;
}

// L2-normalize rows of T and S -> xn (row major) and xnT (transposed).
// Fused: lab[i] = argmax_c labels[i,c] (first-max).
__global__ void k_norm(const float* __restrict__ T, const float* __restrict__ S,
                       const float* __restrict__ labels,
                       float* __restrict__ xn, float* __restrict__ xnT,
                       int* __restrict__ lab) {
    int i = blockIdx.x;
    int mat = blockIdx.y;
    const float* in = mat ? S : T;
    int tid = threadIdx.x;  // 256 threads, row has 512 elems
    if (mat == 0 && tid == 0) {
        float best = labels[i * C];
        int bi = 0;
#pragma unroll
        for (int c = 1; c < C; ++c) {
            float v = labels[i * C + c];
            if (v > best) { best = v; bi = c; }
        }
        lab[i] = bi;
    }
    float v0 = in[i * D + tid];
    float v1 = in[i * D + 256 + tid];
    float ss = v0 * v0 + v1 * v1;
    ss = waveReduceSum(ss);
    __shared__ float lds[4];
    __shared__ float inv_s;
    int wid = tid >> 6, lane = tid & 63;
    if (lane == 0) lds[wid] = ss;
    __syncthreads();
    if (tid == 0) {
        float tot = lds[0] + lds[1] + lds[2] + lds[3];
        inv_s = 1.0f / fmaxf(sqrtf(tot), 1e-12f);
    }
    __syncthreads();
    float inv = inv_s;
    float* xnm = xn + mat * (N * D);
    float* xnTm = xnT + mat * (N * D);
    float a = v0 * inv, b = v1 * inv;
    xnm[i * D + tid] = a;
    xnm[i * D + 256 + tid] = b;
    xnTm[tid * N + i] = a;
    xnTm[(tid + 256) * N + i] = b;
}

// cos rows + classify + pack (d, wp) + row E-means. Block = 4 rows x 256 cols.
__global__ void __launch_bounds__(256) k_cos(
        const float* __restrict__ xn, const float* __restrict__ xnT,
        const int* __restrict__ lab, float2* __restrict__ c2,
        float* __restrict__ Earr, float* __restrict__ cpos) {
    int mat = blockIdx.y;
    int i0 = blockIdx.x * 4;
    int j = threadIdx.x;  // 256
    const float* xnm = xn + mat * (N * D);
    const float* xc = xnT + mat * (N * D);
    __shared__ float rows[D][4];  // [k][r]: float4-aligned broadcast reads
#pragma unroll
    for (int r = 0; r < 4; ++r) {
        rows[j][r] = xnm[(i0 + r) * D + j];
        rows[j + 256][r] = xnm[(i0 + r) * D + 256 + j];
    }
    int labj = lab[j];
    int li0 = lab[i0], li1 = lab[i0 + 1], li2 = lab[i0 + 2], li3 = lab[i0 + 3];
    __syncthreads();

    float a0 = 0.f, a1 = 0.f, a2 = 0.f, a3 = 0.f;
#pragma unroll 8
    for (int k = 0; k < D; ++k) {
        float xb = xc[k * N + j];                 // coalesced
        float4 rr = *(const float4*)&rows[k][0];  // wave-uniform broadcast
        a0 = fmaf(rr.x, xb, a0);
        a1 = fmaf(rr.y, xb, a1);
        a2 = fmaf(rr.z, xb, a2);
        a3 = fmaf(rr.w, xb, a3);
    }
    float wp0 = (labj == li0 && j != i0) ? 1.f : 0.f;
    float wp1 = (labj == li1 && j != i0 + 1) ? 1.f : 0.f;
    float wp2 = (labj == li2 && j != i0 + 2) ? 1.f : 0.f;
    float wp3 = (labj == li3 && j != i0 + 3) ? 1.f : 0.f;
    float2* cm = c2 + mat * (N * N);
    cm[(i0 + 0) * N + j] = make_float2((j == i0 + 0) ? 9.0f : a0, wp0);
    cm[(i0 + 1) * N + j] = make_float2((j == i0 + 1) ? 9.0f : a1, wp1);
    cm[(i0 + 2) * N + j] = make_float2((j == i0 + 2) ? 9.0f : a2, wp2);
    cm[(i0 + 3) * N + j] = make_float2((j == i0 + 3) ? 9.0f : a3, wp3);

    // row E-sums: 12 independent wave reductions (latency overlaps)
    float vA0 = (j != i0 + 0) ? a0 : 0.f;
    float vA1 = (j != i0 + 1) ? a1 : 0.f;
    float vA2 = (j != i0 + 2) ? a2 : 0.f;
    float vA3 = (j != i0 + 3) ? a3 : 0.f;
    float r0 = waveReduceSum(vA0);
    float r1 = waveReduceSum(a0 * wp0);
    float r2 = waveReduceSum(wp0);
    float r3 = waveReduceSum(vA1);
    float r4 = waveReduceSum(a1 * wp1);
    float r5 = waveReduceSum(wp1);
    float r6 = waveReduceSum(vA2);
    float r7 = waveReduceSum(a2 * wp2);
    float r8 = waveReduceSum(wp2);
    float r9 = waveReduceSum(vA3);
    float r10 = waveReduceSum(a3 * wp3);
    float r11 = waveReduceSum(wp3);
    __shared__ float red[4][12];
    int wid = j >> 6, lane = j & 63;
    if (lane == 0) {
        red[wid][0] = r0;  red[wid][1] = r1;  red[wid][2] = r2;
        red[wid][3] = r3;  red[wid][4] = r4;  red[wid][5] = r5;
        red[wid][6] = r6;  red[wid][7] = r7;  red[wid][8] = r8;
        red[wid][9] = r9;  red[wid][10] = r10; red[wid][11] = r11;
    }
    __syncthreads();
    if (j < 4) {
        float sA = 0, sP = 0, cP = 0;
        for (int w = 0; w < 4; ++w) {
            sA += red[w][j * 3 + 0];
            sP += red[w][j * 3 + 1];
            cP += red[w][j * 3 + 2];
        }
        int row = i0 + j;
        Earr[(mat * 2 + 0) * N + row] = sP / cP;
        Earr[(mat * 2 + 1) * N + row] = (sA - sP) / (255.f - cP);
        if (mat == 0) cpos[row] = cP;
    }
}

// Moments per fine cell (m0,m1,m2 for all-nondiag and pos). Pure LDS-atomic
// scatter, per-block partials written with plain coalesced stores.
__global__ void __launch_bounds__(512) k_moments(const float2* __restrict__ c2,
                                                 float* __restrict__ mgp) {
    int mat = blockIdx.y, b = blockIdx.x;  // NPART blocks per mat
    int tid = threadIdx.x;
    __shared__ float mom[6][1024];
    for (int i = tid; i < 6 * 1024; i += 512) (&mom[0][0])[i] = 0.f;
    __syncthreads();
    int base = b * 4096;
#pragma unroll
    for (int it = 0; it < 8; ++it) {
        float2 v = c2[mat * (N * N) + base + it * 512 + tid];
        float d = v.x;
        if (d < 8.f) {  // diag flagged 9
            int j = (int)floorf((d + 1.f) * 500.f);
            j = max(0, min(j, MCELL - 1));
            float del = d - (-1.f + ((float)j + 0.5f) * 0.002f);
            float dd = del * del;
            atomicAdd(&mom[0][j], 1.f);
            atomicAdd(&mom[1][j], del);
            atomicAdd(&mom[2][j], dd);
            if (v.y > 0.f) {
                atomicAdd(&mom[3][j], 1.f);
                atomicAdd(&mom[4][j], del);
                atomicAdd(&mom[5][j], dd);
            }
        }
    }
    __syncthreads();
    float* dst = mgp + (mat * NPART + b) * PSTRIDE;
    for (int i = tid; i < PSTRIDE; i += 512) dst[i] = (&mom[0][0])[i];
}

// Merge partials + convolve with Gaussian (2nd-order moment expansion).
// Block owns its whole mat's hp/hs slice -> plain stores, no memset needed.
// e(d,t) ~= E(q) * (m0 - 100q*m1 + (5000q^2-50)*m2), q = cell_center - t
__global__ void __launch_bounds__(1024) k_conv(const float* __restrict__ mgp,
                                               float* __restrict__ hp,
                                               float* __restrict__ hs) {
    int mat = blockIdx.y;
    int tid = threadIdx.x;
    __shared__ float sm[6][1024];
    float4* smv = (float4*)(&sm[0][0]);  // 1536 float4
    const float4* src = (const float4*)(mgp + (size_t)mat * NPART * PSTRIDE);
    for (int v = tid; v < 1536; v += 1024) {
        float4 acc = make_float4(0.f, 0.f, 0.f, 0.f);
        for (int b = 0; b < NPART; ++b) {
            float4 p = src[b * 1536 + v];
            acc.x += p.x; acc.y += p.y; acc.z += p.z; acc.w += p.w;
        }
        smv[v] = acc;
    }
    __syncthreads();
    float tb = -1.f + 0.002f * (float)tid;  // bin left edge t_k = -1 + 0.002k
    float pa = 0.f, sa = 0.f;
    for (int j = 0; j < MCELL; ++j) {
        float m0 = sm[0][j];
        if (m0 == 0.f) continue;  // wave-uniform skip of empty cells
        float cj = -1.f + ((float)j + 0.5f) * 0.002f;
        float q = cj - tb;
        float q2 = q * q;
        if (q2 < 0.5f) {  // exp(-50*0.5) ~ 1.4e-11: negligible beyond
            float E = __builtin_amdgcn_exp2f(KEXP2 * q2);
            float u = 100.f * q;
            float w2 = fmaf(0.5f * u, u, -50.f);
            sa = fmaf(E, fmaf(w2, sm[2][j], fmaf(-u, sm[1][j], m0)), sa);
            pa = fmaf(E, fmaf(w2, sm[5][j], fmaf(-u, sm[4][j], sm[3][j])), pa);
        }
    }
    if (tid < NBINS) {
        hp[mat * NBINS + tid] = pa;
        hs[mat * NBINS + tid] = sa;
    }
}

// final: counts from cpos, KLs over bins + order terms over rows (double accum)
__global__ void __launch_bounds__(1024) k_final(const float* __restrict__ hp,
                                                const float* __restrict__ hs,
                                                const float* __restrict__ Earr,
                                                const float* __restrict__ cpos,
                                                float* __restrict__ out) {
    int tid = threadIdx.x;
    int wid = tid >> 6, lane = tid & 63;
    __shared__ float cred[16];
    __shared__ float pcnt_s;
    float cv = (tid < N) ? cpos[tid] : 0.f;
    cv = waveReduceSum(cv);
    if (lane == 0) cred[wid] = cv;
    __syncthreads();
    if (tid == 0) {
        float t = 0;
        for (int w = 0; w < 16; ++w) t += cred[w];
        pcnt_s = t;
    }
    __syncthreads();
    float pcnt = pcnt_s;
    float ncnt = 65280.f - pcnt;  // N*N - N - pcnt

    double poskl = 0, negkl = 0, o1 = 0, o2 = 0, o3 = 0;
    if (tid < NBINS) {
        float hpT = hp[0 * NBINS + tid], hsT = hs[0 * NBINS + tid];
        float hpS = hp[1 * NBINS + tid], hsS = hs[1 * NBINS + tid];
        float pt = hpT / pcnt;
        float nt = (hsT - hpT) / ncnt;
        float ps = hpS / pcnt;
        float ns = (hsS - hpS) / ncnt;
        poskl = (double)((pt + EPSF) * (__logf(pt + EPSF) - __logf(ps + EPSF)));
        negkl = (double)((nt + EPSF) * (__logf(nt + EPSF) - __logf(ns + EPSF)));
    }
    if (tid < N) {
        float ept = Earr[0 * N + tid];
        float ent = Earr[1 * N + tid];
        float eps_ = Earr[2 * N + tid];
        float ens = Earr[3 * N + tid];
        o1 = fabs((double)ept - (double)eps_);
        o2 = fabs((double)ent - (double)ens);
        o3 = (double)eps_ - (double)ens;
    }
    poskl = waveReduceSumD(poskl);
    negkl = waveReduceSumD(negkl);
    o1 = waveReduceSumD(o1);
    o2 = waveReduceSumD(o2);
    o3 = waveReduceSumD(o3);
    __shared__ double lds[16][5];
    if (lane == 0) {
        lds[wid][0] = poskl; lds[wid][1] = negkl;
        lds[wid][2] = o1; lds[wid][3] = o2; lds[wid][4] = o3;
    }
    __syncthreads();
    if (tid == 0) {
        double a = 0, b = 0, c = 0, d = 0, e = 0;
        for (int w = 0; w < 16; ++w) {
            a += lds[w][0]; b += lds[w][1]; c += lds[w][2]; d += lds[w][3]; e += lds[w][4];
        }
        double loss = 0.1 * a + 0.02 * b + 0.5 * ((c + d + e) / (double)N);
        out[0] = (float)loss;
    }
}

extern "C" void kernel_launch(void* const* d_in, const int* in_sizes, int n_in,
                              void* d_out, int out_size, void* d_ws, size_t ws_size,
                              hipStream_t stream) {
    const float* T = (const float*)d_in[0];
    const float* S = (const float*)d_in[1];
    const float* labels = (const float*)d_in[2];
    float* out = (float*)d_out;

    float* ws = (float*)d_ws;
    float* xn = ws;                            // 2*N*D = 262144
    float* xnT = xn + 2 * N * D;               // 262144
    float2* c2 = (float2*)(xnT + 2 * N * D);   // 2*N*N float2 = 262144 floats
    float* mgp = (float*)(c2 + 2 * N * N);     // 2*NPART*PSTRIDE = 196608
    float* hp = mgp + 2 * NPART * PSTRIDE;     // 2*NBINS
    float* hs = hp + 2 * NBINS;                // 2*NBINS
    float* Earr = hs + 2 * NBINS;              // 4*N
    float* cpos = Earr + 4 * N;                // N
    int* lab = (int*)(cpos + N);               // N ints

    k_norm<<<dim3(N, 2), 256, 0, stream>>>(T, S, labels, xn, xnT, lab);
    k_cos<<<dim3(N / 4, 2), 256, 0, stream>>>(xn, xnT, lab, c2, Earr, cpos);
    k_moments<<<dim3(NPART, 2), 512, 0, stream>>>(c2, mgp);
    k_conv<<<dim3(1, 2), 1024, 0, stream>>>(mgp, hp, hs);
    k_final<<<1, 1024, 0, stream>>>(hp, hs, Earr, cpos, out);
}

// Round 5
// 53.649 us; speedup vs baseline: 2.3899x; 2.3899x over previous
//
#include <hip/hip_runtime.h>
#include <hip/hip_bf16.h>
#include <math.h>

#define N 256
#define D 512
#define C 16
#define NBINS 1000
#define MCELL 1000
#define MSTRIDE 1024      // per-moment stride inside mg
#define EPSF 1e-9f
// -50/ln(2): exp(-50*q^2) = exp2(KEXP2*q^2)
#define KEXP2 -72.134752f
#define NCB 32            // conv blocks per mat, 32 cells each

__device__ inline float waveReduceSum(float v) {
#pragma unroll
    for (int off = 32; off > 0; off >>= 1) v += __shfl_down(v, off, 64);
    return v;
}
__device__ inline double waveReduceSumD(double v) {
#pragma unroll
    for (int off = 32; off > 0; off >>= 1) v += __shfl_down(v, off, 64);
    return v;
}

// L2-normalize rows of T and S -> xn (row major) and xnT (transposed).
// Fused: argmax labels -> lab; spare blocks zero mg (12288 floats).
__global__ void k_norm(const float* __restrict__ T, const float* __restrict__ S,
                       const float* __restrict__ labels,
                       float* __restrict__ xn, float* __restrict__ xnT,
                       int* __restrict__ lab, float* __restrict__ mg) {
    int i = blockIdx.x;
    int mat = blockIdx.y;
    int tid = threadIdx.x;  // 256
    if (mat == 1 && i < 12) {  // zero mg: 12 blocks x 256 threads x 4 floats
        ((float4*)(mg + i * 1024))[tid] = make_float4(0.f, 0.f, 0.f, 0.f);
    }
    const float* in = mat ? S : T;
    if (mat == 0 && tid == 0) {
        float best = labels[i * C];
        int bi = 0;
#pragma unroll
        for (int c = 1; c < C; ++c) {
            float v = labels[i * C + c];
            if (v > best) { best = v; bi = c; }
        }
        lab[i] = bi;
    }
    float v0 = in[i * D + tid];
    float v1 = in[i * D + 256 + tid];
    float ss = v0 * v0 + v1 * v1;
    ss = waveReduceSum(ss);
    __shared__ float lds[4];
    __shared__ float inv_s;
    int wid = tid >> 6, lane = tid & 63;
    if (lane == 0) lds[wid] = ss;
    __syncthreads();
    if (tid == 0) {
        float tot = lds[0] + lds[1] + lds[2] + lds[3];
        inv_s = 1.0f / fmaxf(sqrtf(tot), 1e-12f);
    }
    __syncthreads();
    float inv = inv_s;
    float* xnm = xn + mat * (N * D);
    float* xnTm = xnT + mat * (N * D);
    float a = v0 * inv, b = v1 * inv;
    xnm[i * D + tid] = a;
    xnm[i * D + 256 + tid] = b;
    xnTm[tid * N + i] = a;
    xnTm[(tid + 256) * N + i] = b;
}

// cos rows + classify + row E-means + moment partial (LDS) + sparse global merge.
// Block = 4 rows x 256 cols.
__global__ void __launch_bounds__(256) k_cos(
        const float* __restrict__ xn, const float* __restrict__ xnT,
        const int* __restrict__ lab, float* __restrict__ mg,
        float* __restrict__ Earr, float* __restrict__ cpos) {
    int mat = blockIdx.y;
    int i0 = blockIdx.x * 4;
    int j = threadIdx.x;  // 256
    const float* xnm = xn + mat * (N * D);
    const float* xc = xnT + mat * (N * D);
    __shared__ float rows[D][4];     // [k][r]: float4 broadcast reads
    __shared__ float mom[6 * 1024];  // m0,m1,m2 (all), m0,m1,m2 (pos)
    for (int i = j; i < 6 * 1024; i += 256) mom[i] = 0.f;
#pragma unroll
    for (int r = 0; r < 4; ++r) {
        rows[j][r] = xnm[(i0 + r) * D + j];
        rows[j + 256][r] = xnm[(i0 + r) * D + 256 + j];
    }
    int labj = lab[j];
    int li0 = lab[i0], li1 = lab[i0 + 1], li2 = lab[i0 + 2], li3 = lab[i0 + 3];
    __syncthreads();

    float a0 = 0.f, a1 = 0.f, a2 = 0.f, a3 = 0.f;
#pragma unroll 8
    for (int k = 0; k < D; ++k) {
        float xb = xc[k * N + j];                 // coalesced
        float4 rr = *(const float4*)&rows[k][0];  // wave-uniform broadcast
        a0 = fmaf(rr.x, xb, a0);
        a1 = fmaf(rr.y, xb, a1);
        a2 = fmaf(rr.z, xb, a2);
        a3 = fmaf(rr.w, xb, a3);
    }
    float av[4] = {a0, a1, a2, a3};
    int liv[4] = {li0, li1, li2, li3};
    float wp[4], vA[4];
#pragma unroll
    for (int r = 0; r < 4; ++r) {
        bool diag = (j == i0 + r);
        wp[r] = (labj == liv[r] && !diag) ? 1.f : 0.f;
        vA[r] = diag ? 0.f : av[r];
        if (!diag) {  // scatter into LDS moment partial
            float d = av[r];
            int jc = (int)floorf((d + 1.f) * 500.f);
            jc = max(0, min(jc, MCELL - 1));
            float del = d - (-1.f + ((float)jc + 0.5f) * 0.002f);
            float dd = del * del;
            atomicAdd(&mom[jc], 1.f);
            atomicAdd(&mom[MSTRIDE + jc], del);
            atomicAdd(&mom[2 * MSTRIDE + jc], dd);
            if (wp[r] > 0.f) {
                atomicAdd(&mom[3 * MSTRIDE + jc], 1.f);
                atomicAdd(&mom[4 * MSTRIDE + jc], del);
                atomicAdd(&mom[5 * MSTRIDE + jc], dd);
            }
        }
    }

    // row E-sums: 12 independent wave reductions
    float r0 = waveReduceSum(vA[0]);
    float r1 = waveReduceSum(av[0] * wp[0]);
    float r2 = waveReduceSum(wp[0]);
    float r3 = waveReduceSum(vA[1]);
    float r4 = waveReduceSum(av[1] * wp[1]);
    float r5 = waveReduceSum(wp[1]);
    float r6 = waveReduceSum(vA[2]);
    float r7 = waveReduceSum(av[2] * wp[2]);
    float r8 = waveReduceSum(wp[2]);
    float r9 = waveReduceSum(vA[3]);
    float r10 = waveReduceSum(av[3] * wp[3]);
    float r11 = waveReduceSum(wp[3]);
    __shared__ float red[4][12];
    int wid = j >> 6, lane = j & 63;
    if (lane == 0) {
        red[wid][0] = r0;  red[wid][1] = r1;  red[wid][2] = r2;
        red[wid][3] = r3;  red[wid][4] = r4;  red[wid][5] = r5;
        red[wid][6] = r6;  red[wid][7] = r7;  red[wid][8] = r8;
        red[wid][9] = r9;  red[wid][10] = r10; red[wid][11] = r11;
    }
    __syncthreads();  // mom atomics done + red visible

    // sparse merge of LDS partial into global mg (~150 occupied cells)
    for (int i = j; i < 6 * 1024; i += 256) {
        float v = mom[i];
        if (v != 0.f) atomicAdd(&mg[mat * 6144 + i], v);
    }
    if (j < 4) {
        float sA = 0, sP = 0, cP = 0;
        for (int w = 0; w < 4; ++w) {
            sA += red[w][j * 3 + 0];
            sP += red[w][j * 3 + 1];
            cP += red[w][j * 3 + 2];
        }
        int row = i0 + j;
        Earr[(mat * 2 + 0) * N + row] = sP / cP;
        Earr[(mat * 2 + 1) * N + row] = (sA - sP) / (255.f - cP);
        if (mat == 0) cpos[row] = cP;
    }
}

// Convolution with Gaussian via 2nd-order moment expansion.
// Block = (32-cell slice, mat); thread = bin; plain-store bin partials.
// e(d,t) ~= E(q) * (m0 - 100q*m1 + (5000q^2-50)*m2), q = cell_center - t
__global__ void __launch_bounds__(1024) k_conv(const float* __restrict__ mg,
                                               float* __restrict__ hpp,
                                               float* __restrict__ hss) {
    int mat = blockIdx.y, b = blockIdx.x;  // NCB blocks per mat
    int tid = threadIdx.x;
    int c0 = b * 32;
    __shared__ float sm[6][32];
    if (tid < 192) {
        int m = tid >> 5, c = tid & 31;
        sm[m][c] = mg[mat * 6144 + m * MSTRIDE + c0 + c];
    }
    __syncthreads();
    float tb = -1.f + 0.002f * (float)tid;  // bin left edge
    float pa = 0.f, sa = 0.f;
#pragma unroll 4
    for (int cc = 0; cc < 32; ++cc) {
        float m0 = sm[0][cc];
        if (m0 == 0.f) continue;  // wave-uniform skip of empty cells
        float cj = -1.f + ((float)(c0 + cc) + 0.5f) * 0.002f;
        float q = cj - tb;
        float q2 = q * q;
        if (q2 < 0.5f) {  // exp(-50*0.5) ~ 1.4e-11: negligible beyond
            float E = __builtin_amdgcn_exp2f(KEXP2 * q2);
            float u = 100.f * q;
            float w2 = fmaf(0.5f * u, u, -50.f);
            sa = fmaf(E, fmaf(w2, sm[2][cc], fmaf(-u, sm[1][cc], m0)), sa);
            pa = fmaf(E, fmaf(w2, sm[5][cc], fmaf(-u, sm[4][cc], sm[3][cc])), pa);
        }
    }
    if (tid < NBINS) {
        hpp[(mat * NCB + b) * NBINS + tid] = pa;
        hss[(mat * NCB + b) * NBINS + tid] = sa;
    }
}

// final: merge bin partials, counts, KLs + order terms (double accum)
__global__ void __launch_bounds__(1024) k_final(const float* __restrict__ hpp,
                                                const float* __restrict__ hss,
                                                const float* __restrict__ Earr,
                                                const float* __restrict__ cpos,
                                                float* __restrict__ out) {
    int tid = threadIdx.x;
    int wid = tid >> 6, lane = tid & 63;
    __shared__ float cred[16];
    __shared__ float pcnt_s;
    float cv = (tid < N) ? cpos[tid] : 0.f;
    cv = waveReduceSum(cv);
    if (lane == 0) cred[wid] = cv;
    __syncthreads();
    if (tid == 0) {
        float t = 0;
        for (int w = 0; w < 16; ++w) t += cred[w];
        pcnt_s = t;
    }
    __syncthreads();
    float pcnt = pcnt_s;
    float ncnt = 65280.f - pcnt;  // N*N - N - pcnt

    double poskl = 0, negkl = 0, o1 = 0, o2 = 0, o3 = 0;
    if (tid < NBINS) {
        float hpT = 0, hsT = 0, hpS = 0, hsS = 0;
#pragma unroll 8
        for (int b = 0; b < NCB; ++b) {
            hpT += hpp[(0 * NCB + b) * NBINS + tid];
            hsT += hss[(0 * NCB + b) * NBINS + tid];
            hpS += hpp[(1 * NCB + b) * NBINS + tid];
            hsS += hss[(1 * NCB + b) * NBINS + tid];
        }
        float pt = hpT / pcnt;
        float nt = (hsT - hpT) / ncnt;
        float ps = hpS / pcnt;
        float ns = (hsS - hpS) / ncnt;
        poskl = (double)((pt + EPSF) * (__logf(pt + EPSF) - __logf(ps + EPSF)));
        negkl = (double)((nt + EPSF) * (__logf(nt + EPSF) - __logf(ns + EPSF)));
    }
    if (tid < N) {
        float ept = Earr[0 * N + tid];
        float ent = Earr[1 * N + tid];
        float eps_ = Earr[2 * N + tid];
        float ens = Earr[3 * N + tid];
        o1 = fabs((double)ept - (double)eps_);
        o2 = fabs((double)ent - (double)ens);
        o3 = (double)eps_ - (double)ens;
    }
    poskl = waveReduceSumD(poskl);
    negkl = waveReduceSumD(negkl);
    o1 = waveReduceSumD(o1);
    o2 = waveReduceSumD(o2);
    o3 = waveReduceSumD(o3);
    __shared__ double lds[16][5];
    if (lane == 0) {
        lds[wid][0] = poskl; lds[wid][1] = negkl;
        lds[wid][2] = o1; lds[wid][3] = o2; lds[wid][4] = o3;
    }
    __syncthreads();
    if (tid == 0) {
        double a = 0, b = 0, c = 0, d = 0, e = 0;
        for (int w = 0; w < 16; ++w) {
            a += lds[w][0]; b += lds[w][1]; c += lds[w][2]; d += lds[w][3]; e += lds[w][4];
        }
        double loss = 0.1 * a + 0.02 * b + 0.5 * ((c + d + e) / (double)N);
        out[0] = (float)loss;
    }
}

extern "C" void kernel_launch(void* const* d_in, const int* in_sizes, int n_in,
                              void* d_out, int out_size, void* d_ws, size_t ws_size,
                              hipStream_t stream) {
    const float* T = (const float*)d_in[0];
    const float* S = (const float*)d_in[1];
    const float* labels = (const float*)d_in[2];
    float* out = (float*)d_out;

    float* ws = (float*)d_ws;
    float* xn = ws;                        // 2*N*D = 262144
    float* xnT = xn + 2 * N * D;           // 262144
    float* mg = xnT + 2 * N * D;           // 2*6*1024 = 12288
    float* hpp = mg + 2 * 6 * MSTRIDE;     // 2*NCB*NBINS = 64000
    float* hss = hpp + 2 * NCB * NBINS;    // 64000
    float* Earr = hss + 2 * NCB * NBINS;   // 4*N
    float* cpos = Earr + 4 * N;            // N
    int* lab = (int*)(cpos + N);           // N ints

    k_norm<<<dim3(N, 2), 256, 0, stream>>>(T, S, labels, xn, xnT, lab, mg);
    k_cos<<<dim3(N / 4, 2), 256, 0, stream>>>(xn, xnT, lab, mg, Earr, cpos);
    k_conv<<<dim3(NCB, 2), 1024, 0, stream>>>(mg, hpp, hss);
    k_final<<<1, 1024, 0, stream>>>(hpp, hss, Earr, cpos, out);
}